// Round 13
// baseline (133.054 us; speedup 1.0000x reference)
//
#include <hip/hip_runtime.h>

// TWO waves (128 threads) per batch element. State: 1024 amps = 8/lane as
// packed float2 (re,im). s = (wv<<9)|(lane<<3)|r : bit9=wave, bits8..3=lane,
// bits2..0=r. Qubit q <-> s-bit (9-q). Gates whose GF(2)-conjugated mask
// contains bit9 (7 of 30) exchange via LDS + barrier; rest are DPP/swizzle/
// bpermute lane ops or in-register r-pairs.
//
// R6 SGPR coeffs 124us; R7/R8 DPP 105us; R9 packed v2 90us; R10 lane-parallel
// gate precompute 72us; R11 funnel reductions 64us; R12 GF(2) CNOT folding
// 55us (VALUBusy 65%, occupancy 28% = grid-capped 16 waves/CU).
// R13: TLP was the limiter -> split each element across 2 waves (8192 waves,
// 32/CU), halving per-wave slots. 7 cross-wave gates via LDS double-barrier.

typedef float v2 __attribute__((ext_vector_type(2)));

// ===== compile-time GF(2) linear algebra on 10-bit indices =====
struct M10 { unsigned row[10]; };
constexpr M10 mident() { M10 m{}; for (int i=0;i<10;++i) m.row[i]=1u<<i; return m; }
constexpr M10 mmul(M10 A, M10 B) {
  M10 C{};
  for (int i=0;i<10;++i){ unsigned x=0; for (int j=0;j<10;++j) if ((A.row[i]>>j)&1u) x ^= B.row[j]; C.row[i]=x; }
  return C;
}
constexpr M10 cnotT(int ctrl, int rng) {
  const int tgt = (ctrl + rng) % 10;
  const int cb = 9 - ctrl, tb = 9 - tgt;
  M10 m = mident(); m.row[tb] = (1u<<tb)|(1u<<cb); return m;
}
constexpr M10 blockPinv(int rng) { M10 m = cnotT(0,rng); for (int c=1;c<10;++c) m = mmul(m, cnotT(c,rng)); return m; }
constexpr M10 blockP(int rng)    { M10 m = cnotT(9,rng); for (int c=8;c>=0;--c) m = mmul(m, cnotT(c,rng)); return m; }
constexpr unsigned mcol(M10 A, int c) { unsigned x=0; for (int i=0;i<10;++i) x |= ((A.row[i]>>c)&1u)<<i; return x; }
constexpr int par(unsigned x){ int p=0; for (int i=0;i<10;++i) p ^= (int)((x>>i)&1u); return p; }
constexpr int topbit3(int x){ int b=0; for (int i=1;i<3;++i) if (x>>i) b=i; return 1<<b; }

constexpr M10 Q1  = blockP(1);
constexpr M10 Q1i = blockPinv(1);
constexpr M10 Q2  = mmul(blockP(2), Q1);
constexpr M10 Q2i = mmul(Q1i, blockPinv(2));
constexpr M10 Q3  = mmul(blockP(3), Q2);
static_assert(mmul(Q1, Q1i).row[0]==1u && mmul(Q1,Q1i).row[9]==(1u<<9), "inv1");
static_assert(mmul(Q2, Q2i).row[0]==1u && mmul(Q2,Q2i).row[7]==(1u<<7), "inv2");
static_assert(par(mcol(Q1i,0)&Q1.row[0]) && par(mcol(Q1i,5)&Q1.row[5]) && par(mcol(Q1i,9)&Q1.row[9]), "dual1");
static_assert(par(mcol(Q2i,0)&Q2.row[0]) && par(mcol(Q2i,4)&Q2.row[4]) && par(mcol(Q2i,9)&Q2.row[9]), "dual2");

// ===== cross-lane xor =====
template<int CTRL>
__device__ __forceinline__ float dppf(float v) {
  return __int_as_float(__builtin_amdgcn_update_dpp(
      0, __float_as_int(v), CTRL, 0xF, 0xF, true));
}
template<int MASK>
__device__ __forceinline__ float xany(float v, int baddr) {
  constexpr int QC[4] = {0, 0xB1, 0x4E, 0x1B};
  if constexpr (MASK == 0) return v;
  else if constexpr (MASK <= 3) return dppf<QC[MASK]>(v);
  else if constexpr (MASK == 4) return dppf<0x141>(dppf<0x1B>(v));
  else if constexpr (MASK == 8) return dppf<0x128>(v);
  else if constexpr (MASK >= 9 && MASK <= 11) return dppf<QC[MASK&3]>(dppf<0x128>(v));
  else if constexpr (MASK < 32) return __int_as_float(__builtin_amdgcn_ds_swizzle(__float_as_int(v), (MASK<<10)|0x1F));
  else return __int_as_float(__builtin_amdgcn_ds_bpermute(baddr, __float_as_int(v)));
}
template<int MASK>
__device__ __forceinline__ v2 xany2(v2 v, int baddr) {
  v2 r; r.x = xany<MASK>(v.x, baddr); r.y = xany<MASK>(v.y, baddr); return r;
}
template<int LM>
__device__ __forceinline__ float xshfl(float v) {
  if constexpr (LM == 1) return dppf<0xB1>(v);
  else if constexpr (LM == 2) return dppf<0x4E>(v);
  else if constexpr (LM == 4) return dppf<0x141>(dppf<0x1B>(v));
  else if constexpr (LM == 8) return dppf<0x128>(v);
  else if constexpr (LM == 16) return __int_as_float(__builtin_amdgcn_ds_swizzle(__float_as_int(v), 0x401F));
  else return __shfl_xor(v, 32);
}
template<int B, int NP>
__device__ __forceinline__ void fstage(float* p, int lane) {
  #pragma unroll
  for (int i = 0; i < NP; ++i) {
    const float send = (lane & B) ? p[i] : p[i + NP];
    const float recv = xshfl<B>(send);
    const float keep = (lane & B) ? p[i + NP] : p[i];
    p[i] = keep + recv;
  }
}
constexpr int holder_lane45(int v) {
  const int a = v >= 24; int r = v - 24 * a;
  const int b = r >= 12; r -= 12 * b;
  const int c = r >= 6;  r -= 6 * c;
  const int d = r >= 3;  r -= 3 * d;
  const int e = r >= 2;  r -= 2 * e;
  return a | (b << 1) | (c << 2) | (d << 3) | (e << 4) | (r << 5);
}
constexpr int holder_lane10(int v) {
  const int a = v >= 5; int r = v - 5 * a;
  const int b = r >= 3; r -= 3 * b;
  const int c = r >= 2; r -= 2 * c;
  return a | (b << 1) | (c << 2) | (r << 3);
}

__device__ __forceinline__ float rfl(float x) {
  return __int_as_float(__builtin_amdgcn_readfirstlane(__float_as_int(x)));
}
#define RLg(g_, x_) __int_as_float(__builtin_amdgcn_readlane(__float_as_int(x_), (g_)))

__device__ __forceinline__ float fast_tanh(float x) {
  return 1.0f - 2.0f / (__expf(2.0f * x) + 1.0f);
}
__device__ __forceinline__ v2 sneg(v2 a) { v2 r; r.x = -a.y; r.y = a.x; return r; }

// ===== conjugated gate: pair-mask M, indicator-mask V (10-bit, s-space) =====
// m00=(ar,ai), m01=(br,bi); m11=conj(m00), m10=-conj(m01).
// h=0: out = ar*a + ai*i*a + br*p + bi*i*p ; h=1: flip signs of ai, br.
template<int M, int V>
__device__ __forceinline__ void gate_g(v2 (&st)[8], int lane, int sidx, float2* xb,
                                       float ar, float ai, float br, float bi) {
  constexpr int MW = (M >> 9) & 1, ML = (M >> 3) & 63, MR = M & 7;
  constexpr int VC = (((V >> 9) & 1) << 6) | ((V >> 3) & 63);   // sidx-mask
  constexpr int VR = V & 7;
  bool hl = false;
  if constexpr (VC != 0) hl = (__builtin_popcount(sidx & VC) & 1) != 0;
  const float aiX = hl ? -ai : ai;
  const float brX = hl ? -br : br;
  if constexpr (MW == 1) {
    // cross-wave: LDS exchange (layout xb[r][tid] -> 2-way bank alias, free)
    #pragma unroll
    for (int r = 0; r < 8; ++r) { float2 t; t.x = st[r].x; t.y = st[r].y; xb[r*128 + sidx] = t; }
    __syncthreads();
    const int ptid = sidx ^ (64 | ML);
    v2 p[8];
    #pragma unroll
    for (int r = 0; r < 8; ++r) { const float2 t = xb[(r^MR)*128 + ptid]; p[r].x = t.x; p[r].y = t.y; }
    #pragma unroll
    for (int r = 0; r < 8; ++r) {
      const v2 a = st[r];
      if ((__builtin_popcount(r & VR) & 1) == 0)
        st[r] = ar*a + aiX*sneg(a) + brX*p[r] + bi*sneg(p[r]);
      else
        st[r] = ar*a - aiX*sneg(a) - brX*p[r] + bi*sneg(p[r]);
    }
    __syncthreads();
  } else if constexpr (MR == 0) {
    int baddr = 0;
    if constexpr (ML >= 32) baddr = (lane ^ ML) << 2;
    #pragma unroll
    for (int r = 0; r < 8; ++r) {
      const v2 p = xany2<ML>(st[r], baddr);
      const v2 a = st[r];
      if ((__builtin_popcount(r & VR) & 1) == 0)
        st[r] = ar*a + aiX*sneg(a) + brX*p + bi*sneg(p);
      else
        st[r] = ar*a - aiX*sneg(a) - brX*p + bi*sneg(p);
    }
  } else {
    constexpr int HB = topbit3(MR);
    int baddr = 0;
    if constexpr (ML >= 32) baddr = (lane ^ ML) << 2;
    #pragma unroll
    for (int r = 0; r < 8; ++r) {
      if ((r & HB) == 0) {
        const int r1 = r ^ MR;
        v2 pa, pb;
        if constexpr (ML == 0) { pa = st[r1]; pb = st[r]; }
        else { pa = xany2<ML>(st[r1], baddr); pb = xany2<ML>(st[r], baddr); }
        const v2 a = st[r], b = st[r1];
        if ((__builtin_popcount(r & VR) & 1) == 0)
          st[r] = ar*a + aiX*sneg(a) + brX*pa + bi*sneg(pa);
        else
          st[r] = ar*a - aiX*sneg(a) - brX*pa + bi*sneg(pa);
        if ((__builtin_popcount(r1 & VR) & 1) == 0)
          st[r1] = ar*b + aiX*sneg(b) + brX*pb + bi*sneg(pb);
        else
          st[r1] = ar*b - aiX*sneg(b) - brX*pb + bi*sneg(pb);
      }
    }
  }
}

// ZZ half-angle binning: qubits 0..6 -> sidx bits 6..0; qubits 7,8,9 -> r bits 2,1,0
template<int I, int J>
__device__ __forceinline__ void pair_accum(float t, int sidx, float& Cc,
                                           float (&dcf)[3], float (&ecf)[3]) {
  if constexpr (J <= 6) {
    const bool diff = (((sidx >> (6 - I)) ^ (sidx >> (6 - J))) & 1) != 0;
    Cc += diff ? -t : t;
  } else if constexpr (I <= 6) {
    const bool b = ((sidx >> (6 - I)) & 1) != 0;
    dcf[J - 7] += b ? -t : t;
  } else {
    constexpr int eb = (I == 7) ? (J - 8) : 2;   // (7,8)->0 (7,9)->1 (8,9)->2
    ecf[eb] = t;
  }
}
#define PACC(v_, i_, j_) pair_accum<i_, j_>(RLg(holder_lane45(v_), tl), sidx, Cc, dcoef, ecoef);

#define GATE0(g_, q_) gate_g<(1<<(9-(q_))), (1<<(9-(q_)))>(st, lane, sidx, xb, \
    RLg(g_,Mr00), RLg(g_,Mi00), RLg(g_,Mr01), RLg(g_,Mi01));
#define GATE1(g_, q_) gate_g<(int)mcol(Q1i,9-(q_)), (int)Q1.row[9-(q_)]>(st, lane, sidx, xb, \
    RLg(g_,Mr00), RLg(g_,Mi00), RLg(g_,Mr01), RLg(g_,Mi01));
#define GATE2(g_, q_) gate_g<(int)mcol(Q2i,9-(q_)), (int)Q2.row[9-(q_)]>(st, lane, sidx, xb, \
    RLg(g_,Mr00), RLg(g_,Mi00), RLg(g_,Mr01), RLg(g_,Mi01));

extern "C" __global__ void __launch_bounds__(128, 8)
qhl_kernel(const float* __restrict__ c_kt, const float* __restrict__ dc_kt,
           const float* __restrict__ vw,  const float* __restrict__ w_proj,
           const float* __restrict__ b_proj, const float* __restrict__ log_alpha,
           float* __restrict__ out) {
  __shared__ float2 xbuf[8 * 128];          // 8 KB: gate exchanges + combines
  float2* xb = xbuf;
  float*  fb = (float*)xbuf;                // 128-float view for combines

  const int sidx = threadIdx.x;             // (wv<<6)|lane
  const int lane = sidx & 63;
  const int bid  = blockIdx.x;

  const float* c   = c_kt  + (size_t)bid * 1280;
  const float* dcp = dc_kt + (size_t)bid * 1280;

  // ---- per-lane gate-matrix precompute (lane g of EACH wave computes gate g)
  float Mr00, Mi00, Mr01, Mi01;
  {
    const int g = lane < 30 ? lane : 0;
    const int l = g / 10, q = g - l * 10;
    const float w0 = vw[g*3+0], w1 = vw[g*3+1], w2 = vw[g*3+2];
    float cY, sY; __sincosf(0.5f*w1, &sY, &cY);
    float ca, sa; __sincosf(0.5f*(w0+w2), &sa, &ca);
    float cb, sb; __sincosf(0.5f*(w0-w2), &sb, &cb);
    const float r00r =  cY*ca, r00i = -cY*sa, r01r = -sY*cb, r01i = -sY*sb;
    if (l == 0) {
      Mr00 = r00r; Mi00 = r00i; Mr01 = r01r; Mi01 = r01i;
    } else {
      const float thq = c[1270 + q], phq = dcp[1270 + q];
      float cy, sy; __sincosf(0.25f * thq, &sy, &cy);
      float cz, sz; __sincosf(0.25f * phq, &sz, &cz);
      const float e00r =  cy*cz, e00i = -cy*sz, e01r = -sy*cz, e01i =  sy*sz;
      const float e10r =  sy*cz, e10i =  sy*sz, e11r =  cy*cz, e11i =  cy*sz;
      Mr00 = r00r*e00r - r00i*e00i + r01r*e10r - r01i*e10i;
      Mi00 = r00r*e00i + r00i*e00r + r01r*e10i + r01i*e10r;
      Mr01 = r00r*e01r - r00i*e01i + r01r*e11r - r01i*e11i;
      Mi01 = r00r*e01i + r00i*e01r + r01r*e11i + r01i*e11r;
    }
  }

  // ---- correlation: thread t = timestep sidx (0..127), 10 features each ----
  float y[10];
  {
    const float2* c0 = (const float2*)(c   + sidx * 10);
    const float2* d0 = (const float2*)(dcp + sidx * 10);
    #pragma unroll
    for (int k = 0; k < 5; ++k) {
      const float2 a0 = c0[k], b0 = d0[k];
      y[2*k]   = a0.x + 0.5f * b0.x;
      y[2*k+1] = a0.y + 0.5f * b0.y;
    }
  }

  // ---- stats: per-wave 10-funnel + cross-wave LDS combine ----
  {
    float mb[6];
    #pragma unroll
    for (int i = 0; i < 5; ++i) {
      const float send = (lane & 1) ? y[i] : y[i + 5];
      const float recv = xshfl<1>(send);
      const float keep = (lane & 1) ? y[i + 5] : y[i];
      mb[i] = keep + recv;
    }
    mb[5] = 0.0f;
    fstage<2, 3>(mb, lane);
    mb[3] = 0.0f;
    fstage<4, 2>(mb, lane);
    fstage<8, 1>(mb, lane);
    mb[0] += xshfl<16>(mb[0]);
    mb[0] += xshfl<32>(mb[0]);
    fb[sidx] = mb[0]; __syncthreads();
    mb[0] = (mb[0] + fb[sidx ^ 64]) * (1.0f / 128.0f); __syncthreads();
    #pragma unroll
    for (int k = 0; k < 10; ++k) y[k] -= RLg(holder_lane10(k), mb[0]);

    float s10[10];
    #pragma unroll
    for (int k = 0; k < 10; ++k) s10[k] = y[k] * y[k];
    #pragma unroll
    for (int i = 0; i < 5; ++i) {
      const float send = (lane & 1) ? s10[i] : s10[i + 5];
      const float recv = xshfl<1>(send);
      const float keep = (lane & 1) ? s10[i + 5] : s10[i];
      mb[i] = keep + recv;
    }
    mb[5] = 0.0f;
    fstage<2, 3>(mb, lane);
    mb[3] = 0.0f;
    fstage<4, 2>(mb, lane);
    fstage<8, 1>(mb, lane);
    mb[0] += xshfl<16>(mb[0]);
    mb[0] += xshfl<32>(mb[0]);
    fb[sidx] = mb[0]; __syncthreads();
    mb[0] += fb[sidx ^ 64]; __syncthreads();
    const float rsv = fminf(__builtin_amdgcn_rsqf(mb[0] * (1.0f / 127.0f)), 1e8f);
    #pragma unroll
    for (int k = 0; k < 10; ++k) y[k] *= RLg(holder_lane10(k), rsv);
  }

  // ---- 45 pair dots: 48-slot per-wave funnel + LDS combine; tanh parallel ----
  const float expA = rfl(__expf(log_alpha[0]));
  float Cc = 0.0f, dcoef[3] = {0, 0, 0}, ecoef[3];
  float tl;
  {
    constexpr int PI_[45] = {0,0,0,0,0,0,0,0,0, 1,1,1,1,1,1,1,1, 2,2,2,2,2,2,2,
                             3,3,3,3,3,3, 4,4,4,4,4, 5,5,5,5, 6,6,6, 7,7, 8};
    constexpr int PJ_[45] = {1,2,3,4,5,6,7,8,9, 2,3,4,5,6,7,8,9, 3,4,5,6,7,8,9,
                             4,5,6,7,8,9, 5,6,7,8,9, 6,7,8,9, 7,8,9, 8,9, 9};
    float p[48];
    #pragma unroll
    for (int v = 0; v < 45; ++v) p[v] = y[PI_[v]] * y[PJ_[v]];
    p[45] = 0.0f; p[46] = 0.0f; p[47] = 0.0f;
    fstage<1, 24>(p, lane);
    fstage<2, 12>(p, lane);
    fstage<4, 6>(p, lane);
    fstage<8, 3>(p, lane);
    p[3] = 0.0f;
    fstage<16, 2>(p, lane);
    fstage<32, 1>(p, lane);
    fb[sidx] = p[0]; __syncthreads();
    p[0] += fb[sidx ^ 64]; __syncthreads();
    tl = -1.5707963267948966f * fast_tanh(p[0] * (expA * (1.0f / 127.0f)));
  }
  PACC(0,0,1) PACC(1,0,2) PACC(2,0,3) PACC(3,0,4) PACC(4,0,5) PACC(5,0,6) PACC(6,0,7) PACC(7,0,8) PACC(8,0,9)
  PACC(9,1,2) PACC(10,1,3) PACC(11,1,4) PACC(12,1,5) PACC(13,1,6) PACC(14,1,7) PACC(15,1,8) PACC(16,1,9)
  PACC(17,2,3) PACC(18,2,4) PACC(19,2,5) PACC(20,2,6) PACC(21,2,7) PACC(22,2,8) PACC(23,2,9)
  PACC(24,3,4) PACC(25,3,5) PACC(26,3,6) PACC(27,3,7) PACC(28,3,8) PACC(29,3,9)
  PACC(30,4,5) PACC(31,4,6) PACC(32,4,7) PACC(33,4,8) PACC(34,4,9)
  PACC(35,5,6) PACC(36,5,7) PACC(37,5,8) PACC(38,5,9)
  PACC(39,6,7) PACC(40,6,8) PACC(41,6,9)
  PACC(42,7,8) PACC(43,7,9)
  PACC(44,8,9)

  // ---- encoding angles -> SGPRs ----
  float th[10], ph[10];
  #pragma unroll
  for (int q = 0; q < 10; ++q) {
    th[q] = rfl(c[1270 + q]);
    ph[q] = rfl(dcp[1270 + q]);
  }

  // ---- per-lane R product (qubits 7,8,9; lane r computes R_r, r=lane&7) ----
  float Rr_l, Ri_l;
  {
    const int rr = lane & 7;
    float prr = 1.0f, pri = 0.0f;
    #pragma unroll
    for (int t = 0; t < 3; ++t) {
      float cy, sy; __sincosf(0.5f * th[7 + t], &sy, &cy);
      float cz, sz; __sincosf(0.5f * ph[7 + t], &sz, &cz);
      const bool b = ((rr >> (2 - t)) & 1) != 0;
      const float fr = b ? sy * cz : cy * cz;
      const float fi = b ? sy * sz : -cy * sz;
      const float nr = prr * fr - pri * fi;
      pri = prr * fi + pri * fr;
      prr = nr;
    }
    Rr_l = prr; Ri_l = pri;
  }

  // ---- initial state: qubit0 from wave bit, qubits 1..6 from lane bits ----
  v2 st[8];
  {
    v2 L; L.x = 1.0f; L.y = 0.0f;
    #pragma unroll
    for (int q = 0; q < 7; ++q) {
      float cy, sy; __sincosf(0.5f * th[q], &sy, &cy);
      float cz, sz; __sincosf(0.5f * ph[q], &sz, &cz);
      const bool b = ((sidx >> (6 - q)) & 1) != 0;
      const float zr = b ? sy * cz : cy * cz;
      const float zi = b ? sy * sz : -cy * sz;
      L = zr * L + zi * sneg(L);
    }
    #pragma unroll
    for (int r = 0; r < 8; ++r) {
      const int b2 = (r >> 2) & 1, b1 = (r >> 1) & 1, b0 = r & 1;
      const float Rr = RLg(r, Rr_l);
      const float Ri = RLg(r, Ri_l);
      float h = Cc;
      h += b2 ? -dcoef[0] : dcoef[0];
      h += b1 ? -dcoef[1] : dcoef[1];
      h += b0 ? -dcoef[2] : dcoef[2];
      h += (b2 ^ b1) ? -ecoef[0] : ecoef[0];
      h += (b2 ^ b0) ? -ecoef[1] : ecoef[1];
      h += (b1 ^ b0) ? -ecoef[2] : ecoef[2];
      float sn, cs; __sincosf(h, &sn, &cs);
      const v2 p = cs * L + sn * sneg(L);
      st[r] = Rr * p + Ri * sneg(p);
    }
  }

  // ---- layer 0 (standard frame) ----
  GATE0(0,0) GATE0(1,1) GATE0(2,2) GATE0(3,3) GATE0(4,4)
  GATE0(5,5) GATE0(6,6) GATE0(7,7) GATE0(8,8) GATE0(9,9)
  // ---- layer 1 conjugated by Q1 ----
  GATE1(10,0) GATE1(11,1) GATE1(12,2) GATE1(13,3) GATE1(14,4)
  GATE1(15,5) GATE1(16,6) GATE1(17,7) GATE1(18,8) GATE1(19,9)
  // ---- layer 2 conjugated by Q2 ----
  GATE2(20,0) GATE2(21,1) GATE2(22,2) GATE2(23,3) GATE2(24,4)
  GATE2(25,5) GATE2(26,6) GATE2(27,7) GATE2(28,8) GATE2(29,9)
  // (CNOT block rng=3 folded into measurement signs via Q3)

  // ---- measurement: Q3-row parities, per-wave funnel, LDS combine ----
  float e[10] = {0,0,0,0,0,0,0,0,0,0};
  #pragma unroll
  for (int r = 0; r < 8; ++r) {
    const v2 sq = st[r] * st[r];
    const float pp = sq.x + sq.y;
    #pragma unroll
    for (int q = 0; q < 10; ++q) {
      const bool s = (__builtin_popcount(r & (int)(Q3.row[9-q] & 7u)) & 1) != 0;
      e[q] += s ? -pp : pp;
    }
  }
  float mv[10];
  #pragma unroll
  for (int q = 0; q < 10; ++q) {
    const int wl = (int)((((Q3.row[9-q] >> 9) & 1u) << 6) | ((Q3.row[9-q] >> 3) & 63u));
    const bool sl = wl ? ((__builtin_popcount(sidx & wl) & 1) != 0) : false;
    mv[q] = sl ? -e[q] : e[q];
  }
  {
    float fbv[6];
    #pragma unroll
    for (int i = 0; i < 5; ++i) {
      const float send = (lane & 1) ? mv[i] : mv[i + 5];
      const float recv = xshfl<1>(send);
      const float keep = (lane & 1) ? mv[i + 5] : mv[i];
      fbv[i] = keep + recv;
    }
    fbv[5] = 0.0f;
    fstage<2, 3>(fbv, lane);
    fbv[3] = 0.0f;
    fstage<4, 2>(fbv, lane);
    fstage<8, 1>(fbv, lane);
    fbv[0] += xshfl<16>(fbv[0]);
    fbv[0] += xshfl<32>(fbv[0]);
    fb[sidx] = fbv[0]; __syncthreads();
    fbv[0] += fb[sidx ^ 64];
    float ev[10];
    #pragma unroll
    for (int k = 0; k < 10; ++k) ev[k] = RLg(holder_lane10(k), fbv[0]);
    if (sidx < 3) {
      float acc = b_proj[sidx];
      #pragma unroll
      for (int i = 0; i < 10; ++i) acc += w_proj[sidx * 10 + i] * ev[i];
      out[(size_t)bid * 3 + sidx] = acc;
    }
  }
}

extern "C" void kernel_launch(void* const* d_in, const int* in_sizes, int n_in,
                              void* d_out, int out_size, void* d_ws, size_t ws_size,
                              hipStream_t stream) {
  (void)in_sizes; (void)n_in; (void)d_ws; (void)ws_size; (void)out_size;
  const float* c_kt      = (const float*)d_in[0];
  const float* dc_kt     = (const float*)d_in[1];
  const float* vw        = (const float*)d_in[2];
  const float* w_proj    = (const float*)d_in[3];
  const float* b_proj    = (const float*)d_in[4];
  const float* log_alpha = (const float*)d_in[5];
  float* out = (float*)d_out;
  // 4096 batch elems, 1 element per 128-thread block (2 waves)
  qhl_kernel<<<dim3(4096), dim3(128), 0, stream>>>(c_kt, dc_kt, vw, w_proj,
                                                   b_proj, log_alpha, out);
}